// Round 4
// baseline (808.482 us; speedup 1.0000x reference)
//
#include <hip/hip_runtime.h>
#include <cstdint>
#include <cstddef>

// ---------------- common helpers ----------------

#define GAS __attribute__((address_space(1)))
#define LAS __attribute__((address_space(3)))

typedef __bf16 bf16x8 __attribute__((ext_vector_type(8)));
typedef float  f32x4  __attribute__((ext_vector_type(4)));
typedef unsigned short u16x8 __attribute__((ext_vector_type(8)));

__device__ __forceinline__ unsigned short f2bf(float f) {
    // round-to-nearest-even float -> bf16 bits (finite inputs only)
    unsigned int u = __float_as_uint(f);
    u += 0x7FFFu + ((u >> 16) & 1u);
    return (unsigned short)(u >> 16);
}
__device__ __forceinline__ float bf2f(unsigned short h) {
    return __uint_as_float(((unsigned int)h) << 16);
}

// ---------------- problem constants ----------------
// B=4096, S=128, E=1024, H=4096, H2=2048, NCLS=3, VOCAB=50257
static constexpr int BB = 4096;
static constexpr int SS = 128;
static constexpr int EE = 1024;
static constexpr int HH = 4096;
static constexpr int H2D = 2048;
static constexpr int VOCAB = 50257;

// ---------------- workspace layout (bytes) ----------------
// sums[0..2] then 1536 per-block partials. H2 overlays X+q1 (dead after gemm1).
static constexpr size_t OFF_S    = 0;                                  // 3 + 1536 doubles
static constexpr size_t OFF_X    = 16384;                              // 4096x1024 bf16 = 8 MiB
static constexpr size_t OFF_Q1   = OFF_X + (size_t)BB * EE * 2;        // 4096x1024 bf16 = 8 MiB
static constexpr size_t OFF_Q2   = OFF_Q1 + (size_t)HH * EE * 2;       // 2048x4096 bf16 = 16 MiB
static constexpr size_t OFF_C    = OFF_Q2 + (size_t)H2D * HH * 2;      // 4096x4096 f32 = 64 MiB
static constexpr size_t OFF_H1   = OFF_C + (size_t)BB * HH * 4;        // 4096x4096 bf16 = 32 MiB
static constexpr size_t OFF_H2   = OFF_X;                              // 4096x2048 bf16 = 16 MiB (overlay)
// total ws ~ 128.02 MiB

// ---------------- kernels ----------------

// stage 1: per-block |w| partial sums, no atomics.
// blocks 0..511 -> w1 partials part[0..511]; 512..1535 -> w2 partials part[512..1535]
__global__ __launch_bounds__(256) void absum_part(const float* __restrict__ w1,
                                                  const float* __restrict__ w2,
                                                  double* __restrict__ part) {
    const int bid = blockIdx.x;
    const float* w; int n4; int b0; int nb;
    if (bid < 512) { w = w1; n4 = HH * EE / 4;  b0 = bid;       nb = 512;  }
    else           { w = w2; n4 = H2D * HH / 4; b0 = bid - 512; nb = 1024; }
    const int tid = threadIdx.x;
    const int lane = tid & 63, wid = tid >> 6;
    double acc = 0.0;
    for (int i = b0 * 256 + tid; i < n4; i += nb * 256) {
        const float4 v = ((const float4*)w)[i];
        acc += (double)fabsf(v.x) + (double)fabsf(v.y) +
               (double)fabsf(v.z) + (double)fabsf(v.w);
    }
    for (int o = 32; o; o >>= 1) acc += __shfl_down(acc, o);
    __shared__ double r[4];
    if (lane == 0) r[wid] = acc;
    __syncthreads();
    if (tid == 0) part[bid] = r[0] + r[1] + r[2] + r[3];
}

// stage 2: reduce partials -> sums[0..1]; block 2 does w3 directly -> sums[2]
__global__ __launch_bounds__(256) void reduce_sums(const double* __restrict__ part,
                                                   const float* __restrict__ w3,
                                                   double* __restrict__ sums) {
    const int bid = blockIdx.x, tid = threadIdx.x;
    const int lane = tid & 63, wid = tid >> 6;
    double acc = 0.0;
    if (bid == 0) {
        acc = part[tid] + part[tid + 256];
    } else if (bid == 1) {
        acc = part[512 + tid] + part[768 + tid] + part[1024 + tid] + part[1280 + tid];
    } else {
        for (int i = tid; i < 3 * H2D; i += 256) acc += (double)fabsf(w3[i]);
    }
    for (int o = 32; o; o >>= 1) acc += __shfl_down(acc, o);
    __shared__ double r[4];
    if (lane == 0) r[wid] = acc;
    __syncthreads();
    if (tid == 0) sums[bid] = r[0] + r[1] + r[2] + r[3];
}

// quantize w1 and w2 to ternary bf16 {-1,0,+1}, vectorized 8 elems/thread
__global__ __launch_bounds__(256) void quant_all(const float* __restrict__ w1,
                                                 const float* __restrict__ w2,
                                                 const double* __restrict__ sums,
                                                 unsigned short* __restrict__ q1,
                                                 unsigned short* __restrict__ q2) {
    const int bid = blockIdx.x;
    const float* w; int n8; unsigned short* q; int b0; int nb; double ssum; double dn;
    if (bid < 2048) { w = w1; n8 = HH * EE / 8;  q = q1; b0 = bid;        nb = 2048; ssum = sums[0]; dn = (double)HH * EE;  }
    else            { w = w2; n8 = H2D * HH / 8; q = q2; b0 = bid - 2048; nb = 4096; ssum = sums[1]; dn = (double)H2D * HH; }
    const float inv_s = (float)(dn / ssum);
    for (int i = b0 * 256 + threadIdx.x; i < n8; i += nb * 256) {
        const float4 v0 = ((const float4*)w)[2 * i];
        const float4 v1 = ((const float4*)w)[2 * i + 1];
        union { unsigned short u[8]; uint4 p; } r;
        const float a[8] = {v0.x, v0.y, v0.z, v0.w, v1.x, v1.y, v1.z, v1.w};
        #pragma unroll
        for (int j = 0; j < 8; ++j)
            r.u[j] = f2bf(rintf(fminf(1.f, fmaxf(-1.f, a[j] * inv_s))));
        ((uint4*)q)[i] = r.p;
    }
}

// fp32 embedding gather + masked mean pool; 2 output rows per block.
// Per-row counting sort of the 128 ids by table window (id>>9 = 512-row/2 MiB
// windows): the co-resident grid sweeps the 206 MB fp32 table in ascending
// order, so each XCD's L2 holds the active window; HBM sees ~1 table sweep.
__global__ __launch_bounds__(256) void pool_kernel(const int* __restrict__ ids,
                                                   const float* __restrict__ emb,
                                                   unsigned short* __restrict__ X) {
    const int tid = threadIdx.x;
    const int row = tid >> 7;           // 0/1 (wave-uniform: 2 waves per row)
    const int t   = tid & 127;
    __shared__ int sid[256];
    __shared__ int sorted_ids[2][128];
    __shared__ int cnt[2][128];
    __shared__ int pos[2][128];
    __shared__ int nz[2];
    sid[tid] = ids[(size_t)blockIdx.x * 256 + tid];
    cnt[row][t] = 0;
    if (tid < 2) nz[tid] = 0;
    __syncthreads();
    const int myid = sid[tid];
    const int ph = myid >> 9;           // 0..98 (VOCAB/512)
    atomicAdd(&cnt[row][ph], 1);
    if (myid != 0) atomicAdd(&nz[row], 1);
    __syncthreads();
    if (tid < 2) {
        int s = 0;
        #pragma unroll
        for (int p = 0; p < 128; ++p) { pos[tid][p] = s; s += cnt[tid][p]; }
    }
    __syncthreads();
    const int where = atomicAdd(&pos[row][ph], 1);
    sorted_ids[row][where] = myid;
    __syncthreads();

    const int col = t * 8;              // 8 floats per thread
    float a[8] = {};
    #pragma unroll 8
    for (int s = 0; s < 128; ++s) {
        const int id = sorted_ids[row][s];          // broadcast LDS read
        const float4* p = (const float4*)(emb + (size_t)id * EE + col);
        const float4 v0 = p[0];
        const float4 v1 = p[1];
        a[0] += v0.x; a[1] += v0.y; a[2] += v0.z; a[3] += v0.w;
        a[4] += v1.x; a[5] += v1.y; a[6] += v1.z; a[7] += v1.w;
    }
    const int c = nz[row];
    const float inv = 1.f / (float)(c ? c : 1);
    u16x8 ov;
    #pragma unroll
    for (int j = 0; j < 8; ++j) ov[j] = f2bf(a[j] * inv);
    const int b = blockIdx.x * 2 + row;
    *(u16x8*)(X + (size_t)b * EE + col) = ov;
}

// C[M,N] = A[M,K] * B[N,K]^T  (bf16 in, fp32 out). M%128==0, N%128==0, K%32==0.
// m97 structure: 128x128 tile, BK=32, global_load_lds width 16, 4 waves x (4x4) 16x16x32 MFMA.
__global__ __launch_bounds__(256) void gemm_bt(const unsigned short* __restrict__ A,
                                               const unsigned short* __restrict__ B,
                                               float* __restrict__ C, int M, int N, int K) {
    __shared__ unsigned short sA[128 * 32];
    __shared__ unsigned short sB[128 * 32];
    const int tid  = threadIdx.x;
    const int wid  = tid >> 6;
    const int lane = tid & 63;
    const int wm = wid >> 1, wn = wid & 1;
    const int quad = lane >> 4;
    const int l16  = lane & 15;
    const int mBase = blockIdx.y * 128;
    const int nBase = blockIdx.x * 128;

    f32x4 acc[4][4] = {};

    const int srow = tid >> 2;            // 0..63
    const int scol = (tid & 3) * 8;       // element col within BK=32
    const size_t aOff0 = (size_t)(mBase + srow) * K + scol;
    const size_t aOff1 = aOff0 + (size_t)64 * K;
    const size_t bOff0 = (size_t)(nBase + srow) * K + scol;
    const size_t bOff1 = bOff0 + (size_t)64 * K;
    unsigned short* ldsA0 = &sA[wid * 512];
    unsigned short* ldsA1 = &sA[2048 + wid * 512];
    unsigned short* ldsB0 = &sB[wid * 512];
    unsigned short* ldsB1 = &sB[2048 + wid * 512];

    for (int k0 = 0; k0 < K; k0 += 32) {
        __syncthreads();
        __builtin_amdgcn_global_load_lds((const GAS void*)(A + aOff0 + k0), (LAS void*)ldsA0, 16, 0, 0);
        __builtin_amdgcn_global_load_lds((const GAS void*)(A + aOff1 + k0), (LAS void*)ldsA1, 16, 0, 0);
        __builtin_amdgcn_global_load_lds((const GAS void*)(B + bOff0 + k0), (LAS void*)ldsB0, 16, 0, 0);
        __builtin_amdgcn_global_load_lds((const GAS void*)(B + bOff1 + k0), (LAS void*)ldsB1, 16, 0, 0);
        __syncthreads();

        bf16x8 af[4], bfr[4];
        #pragma unroll
        for (int i = 0; i < 4; ++i) {
            const int rowA = wm * 64 + i * 16 + l16;
            af[i]  = *(const bf16x8*)(&sA[rowA * 32 + quad * 8]);
            const int rowB = wn * 64 + i * 16 + l16;
            bfr[i] = *(const bf16x8*)(&sB[rowB * 32 + quad * 8]);
        }
        #pragma unroll
        for (int i = 0; i < 4; ++i)
            #pragma unroll
            for (int j = 0; j < 4; ++j)
                acc[i][j] = __builtin_amdgcn_mfma_f32_16x16x32_bf16(af[i], bfr[j], acc[i][j], 0, 0, 0);
    }

    // epilogue: C/D layout col=lane&15, row=(lane>>4)*4+reg
    #pragma unroll
    for (int i = 0; i < 4; ++i) {
        const int row0 = mBase + wm * 64 + i * 16 + quad * 4;
        #pragma unroll
        for (int j = 0; j < 4; ++j) {
            const int col = nBase + wn * 64 + j * 16 + l16;
            #pragma unroll
            for (int r = 0; r < 4; ++r)
                C[(size_t)(row0 + r) * N + col] = acc[i][j][r];
        }
    }
}

// y = C*s + bias; layernorm over row; gelu(exact); write bf16
__global__ __launch_bounds__(256) void ln_gelu_kernel(const float* __restrict__ Cm,
                                                      const double* __restrict__ ssum, double nw,
                                                      const float* __restrict__ bias,
                                                      const float* __restrict__ gamma,
                                                      const float* __restrict__ beta,
                                                      unsigned short* __restrict__ H, int N) {
    __shared__ float buf[4096];
    __shared__ float redS[4], redQ[4];
    const int row = blockIdx.x, tid = threadIdx.x;
    const int lane = tid & 63, wid = tid >> 6;
    const float s = (float)(ssum[0] / nw);
    float ps = 0.f, pq = 0.f;
    for (int c = tid; c < N; c += 256) {
        const float y = Cm[(size_t)row * N + c] * s + bias[c];
        buf[c] = y;
        ps += y; pq += y * y;
    }
    for (int o = 32; o; o >>= 1) { ps += __shfl_down(ps, o); pq += __shfl_down(pq, o); }
    if (lane == 0) { redS[wid] = ps; redQ[wid] = pq; }
    __syncthreads();
    const float sum = redS[0] + redS[1] + redS[2] + redS[3];
    const float sq  = redQ[0] + redQ[1] + redQ[2] + redQ[3];
    const float mu  = sum / (float)N;
    float var = sq / (float)N - mu * mu;
    var = fmaxf(var, 0.f);
    const float inv = rsqrtf(var + 1e-5f);
    for (int c = tid; c < N; c += 256) {
        const float y = (buf[c] - mu) * inv * gamma[c] + beta[c];
        const float g = 0.5f * y * (1.f + erff(y * 0.70710678118654752f));
        H[(size_t)row * N + c] = f2bf(g);
    }
}

// logits[row, 0..2] = H2[row,:] . ternary(w3)[c,:] + b3  (w3 quantized on the fly)
__global__ __launch_bounds__(256) void final_kernel(const unsigned short* __restrict__ H2,
                                                    const float* __restrict__ w3,
                                                    const double* __restrict__ ssum,
                                                    const float* __restrict__ b3,
                                                    float* __restrict__ out) {
    const int row = blockIdx.x, tid = threadIdx.x;
    const int lane = tid & 63, wid = tid >> 6;
    const float inv_s3 = (float)((double)(3 * H2D) / ssum[0]);
    float a0 = 0.f, a1 = 0.f, a2 = 0.f;
    for (int k = tid; k < H2D; k += 256) {
        const float h = bf2f(H2[(size_t)row * H2D + k]);
        const float q0 = rintf(fminf(1.f, fmaxf(-1.f, w3[k] * inv_s3)));
        const float q1 = rintf(fminf(1.f, fmaxf(-1.f, w3[H2D + k] * inv_s3)));
        const float q2 = rintf(fminf(1.f, fmaxf(-1.f, w3[2 * H2D + k] * inv_s3)));
        a0 += h * q0; a1 += h * q1; a2 += h * q2;
    }
    for (int o = 32; o; o >>= 1) {
        a0 += __shfl_down(a0, o); a1 += __shfl_down(a1, o); a2 += __shfl_down(a2, o);
    }
    __shared__ float r[3][4];
    if (lane == 0) { r[0][wid] = a0; r[1][wid] = a1; r[2][wid] = a2; }
    __syncthreads();
    if (tid < 3) {
        const float s3 = (float)(ssum[0] / (double)(3 * H2D));
        out[(size_t)row * 3 + tid] =
            (r[tid][0] + r[tid][1] + r[tid][2] + r[tid][3]) * s3 + b3[tid];
    }
}

// ---------------- launch ----------------

extern "C" void kernel_launch(void* const* d_in, const int* in_sizes, int n_in,
                              void* d_out, int out_size, void* d_ws, size_t ws_size,
                              hipStream_t stream) {
    const int*   ids = (const int*)d_in[0];
    const float* emb = (const float*)d_in[1];
    const float* w1  = (const float*)d_in[2];
    const float* b1  = (const float*)d_in[3];
    const float* w2  = (const float*)d_in[4];
    const float* b2  = (const float*)d_in[5];
    const float* w3  = (const float*)d_in[6];
    const float* b3  = (const float*)d_in[7];
    const float* g1  = (const float*)d_in[8];
    const float* be1 = (const float*)d_in[9];
    const float* g2  = (const float*)d_in[10];
    const float* be2 = (const float*)d_in[11];
    float* out = (float*)d_out;
    char* ws = (char*)d_ws;

    double*         sums = (double*)(ws + OFF_S);      // [0..2] sums, [3..] partials
    double*         part = sums + 8;
    unsigned short* X    = (unsigned short*)(ws + OFF_X);
    unsigned short* q1   = (unsigned short*)(ws + OFF_Q1);
    unsigned short* q2   = (unsigned short*)(ws + OFF_Q2);
    float*          Cbuf = (float*)(ws + OFF_C);
    unsigned short* H1   = (unsigned short*)(ws + OFF_H1);
    unsigned short* H2   = (unsigned short*)(ws + OFF_H2);

    // scales (atomic-free two-stage)
    absum_part<<<1536, 256, 0, stream>>>(w1, w2, part);
    reduce_sums<<<3, 256, 0, stream>>>(part, w3, sums);

    // gather/pool straight from fp32 table (sorted windows)
    pool_kernel<<<BB / 2, 256, 0, stream>>>(ids, emb, X);

    // ternary quant
    quant_all<<<6144, 256, 0, stream>>>(w1, w2, sums, q1, q2);

    // MLP
    gemm_bt<<<dim3(HH / 128, BB / 128), 256, 0, stream>>>(X, q1, Cbuf, BB, HH, EE);
    ln_gelu_kernel<<<BB, 256, 0, stream>>>(Cbuf, sums + 0, (double)HH * (double)EE,
                                           b1, g1, be1, H1, HH);
    gemm_bt<<<dim3(H2D / 128, BB / 128), 256, 0, stream>>>(H1, q2, Cbuf, BB, H2D, HH);
    ln_gelu_kernel<<<BB, 256, 0, stream>>>(Cbuf, sums + 1, (double)H2D * (double)HH,
                                           b2, g2, be2, H2, H2D);
    final_kernel<<<BB, 256, 0, stream>>>(H2, w3, sums + 2, b3, out);
}

// Round 6
// 709.186 us; speedup vs baseline: 1.1400x; 1.1400x over previous
//
#include <hip/hip_runtime.h>
#include <cstdint>
#include <cstddef>

// ---------------- common helpers ----------------

#define GAS __attribute__((address_space(1)))
#define LAS __attribute__((address_space(3)))

typedef __bf16 bf16x8 __attribute__((ext_vector_type(8)));
typedef float  f32x4  __attribute__((ext_vector_type(4)));
typedef unsigned short u16x8 __attribute__((ext_vector_type(8)));

__device__ __forceinline__ unsigned short f2bf(float f) {
    unsigned int u = __float_as_uint(f);
    u += 0x7FFFu + ((u >> 16) & 1u);
    return (unsigned short)(u >> 16);
}
__device__ __forceinline__ float bf2f(unsigned short h) {
    return __uint_as_float(((unsigned int)h) << 16);
}

// ---------------- problem constants ----------------
static constexpr int BB = 4096;
static constexpr int SS = 128;
static constexpr int EE = 1024;
static constexpr int HH = 4096;
static constexpr int H2D = 2048;
static constexpr int VOCAB = 50257;

// ---------------- workspace layout (bytes) ----------------
// embh (bf16 table, 98.2 MiB) is dead after pool; its region is re-carved:
//   q1  [0,8M)   q2 [8M,24M)   C1 bf16 [24M,56M)
//   Cp  f32 64 MiB [24M,88M): split-K partials, z=0 [24M,56M) overlays dead C1,
//                             z=1 [56M,88M). All inside embh's 98.2 MiB.
//   H2 bf16 overlays q1/q2 [0,16M) (dead after their gemms)
// H1 lives AFTER embh: [98.2M, 130.2M) — never touched by the above.
static constexpr size_t MiB      = 1024 * 1024;
static constexpr size_t OFF_S    = 0;                          // sums + partials (~33 KB)
static constexpr size_t OFF_X    = 65536;                      // 8 MiB
static constexpr size_t OFF_EMBH = OFF_X + (size_t)BB * EE * 2;
static constexpr size_t SZ_EMBH  = (size_t)VOCAB * EE * 2;     // 98.2 MiB
static constexpr size_t OFF_Q1   = OFF_EMBH;
static constexpr size_t OFF_Q2   = OFF_EMBH + 8 * MiB;
static constexpr size_t OFF_C1   = OFF_EMBH + 24 * MiB;        // bf16 4096x4096 = 32 MiB
static constexpr size_t OFF_C2   = OFF_EMBH + 24 * MiB;        // f32 2x(4096x2048) = 64 MiB
static constexpr size_t OFF_H2   = OFF_EMBH;                   // bf16 16 MiB (overlay q1/q2)
static constexpr size_t OFF_H1   = OFF_EMBH + SZ_EMBH;         // bf16 32 MiB
// total ~ 138.3 MiB (same footprint as rounds 2/3, which fit)

// ---------------- kernels ----------------

// fused, load-balanced: every block converts an emb slice to bf16 AND sums |w1|,|w2|
// slices into per-block partials (atomic-free).
__global__ __launch_bounds__(256) void prep2_kernel(const float* __restrict__ e,
                                                    unsigned short* __restrict__ o,
                                                    const float* __restrict__ w1,
                                                    const float* __restrict__ w2,
                                                    double* __restrict__ part1,
                                                    double* __restrict__ part2) {
    const int bid = blockIdx.x;        // grid = 2048
    const int tid = threadIdx.x;
    // --- emb -> bf16 (grid-stride over uint4 groups of 8 elems) ---
    const int n8 = (VOCAB * EE) / 8;   // 6,432,896
    for (int i = bid * 256 + tid; i < n8; i += 2048 * 256) {
        const float4 v0 = ((const float4*)e)[2 * i];
        const float4 v1 = ((const float4*)e)[2 * i + 1];
        union { unsigned short u[8]; uint4 q; } r;
        r.u[0] = f2bf(v0.x); r.u[1] = f2bf(v0.y); r.u[2] = f2bf(v0.z); r.u[3] = f2bf(v0.w);
        r.u[4] = f2bf(v1.x); r.u[5] = f2bf(v1.y); r.u[6] = f2bf(v1.z); r.u[7] = f2bf(v1.w);
        ((uint4*)o)[i] = r.q;
    }
    // --- |w1| and |w2| partials ---
    const int lane = tid & 63, wid = tid >> 6;
    double a1 = 0.0, a2 = 0.0;
    const int n41 = HH * EE / 4;       // 1,048,576 float4s
    for (int i = bid * 256 + tid; i < n41; i += 2048 * 256) {
        const float4 v = ((const float4*)w1)[i];
        a1 += (double)fabsf(v.x) + (double)fabsf(v.y) + (double)fabsf(v.z) + (double)fabsf(v.w);
    }
    const int n42 = H2D * HH / 4;      // 2,097,152 float4s
    for (int i = bid * 256 + tid; i < n42; i += 2048 * 256) {
        const float4 v = ((const float4*)w2)[i];
        a2 += (double)fabsf(v.x) + (double)fabsf(v.y) + (double)fabsf(v.z) + (double)fabsf(v.w);
    }
    for (int off = 32; off; off >>= 1) { a1 += __shfl_down(a1, off); a2 += __shfl_down(a2, off); }
    __shared__ double r1[4], r2[4];
    if (lane == 0) { r1[wid] = a1; r2[wid] = a2; }
    __syncthreads();
    if (tid == 0) {
        part1[bid] = r1[0] + r1[1] + r1[2] + r1[3];
        part2[bid] = r2[0] + r2[1] + r2[2] + r2[3];
    }
}

// reduce partials -> sums[0..1]; block 2 sums |w3| -> sums[2]
__global__ __launch_bounds__(256) void reduce_sums(const double* __restrict__ part1,
                                                   const double* __restrict__ part2,
                                                   const float* __restrict__ w3,
                                                   double* __restrict__ sums) {
    const int bid = blockIdx.x, tid = threadIdx.x;
    const int lane = tid & 63, wid = tid >> 6;
    double acc = 0.0;
    if (bid == 0) {
        for (int i = tid; i < 2048; i += 256) acc += part1[i];
    } else if (bid == 1) {
        for (int i = tid; i < 2048; i += 256) acc += part2[i];
    } else {
        for (int i = tid; i < 3 * H2D; i += 256) acc += (double)fabsf(w3[i]);
    }
    for (int o = 32; o; o >>= 1) acc += __shfl_down(acc, o);
    __shared__ double r[4];
    if (lane == 0) r[wid] = acc;
    __syncthreads();
    if (tid == 0) sums[bid] = r[0] + r[1] + r[2] + r[3];
}

// quantize w1 and w2 to ternary bf16 {-1,0,+1}, vectorized 8 elems/thread
__global__ __launch_bounds__(256) void quant_all(const float* __restrict__ w1,
                                                 const float* __restrict__ w2,
                                                 const double* __restrict__ sums,
                                                 unsigned short* __restrict__ q1,
                                                 unsigned short* __restrict__ q2) {
    const int bid = blockIdx.x;
    const float* w; int n8; unsigned short* q; int b0; int nb; double ssum; double dn;
    if (bid < 2048) { w = w1; n8 = HH * EE / 8;  q = q1; b0 = bid;        nb = 2048; ssum = sums[0]; dn = (double)HH * EE;  }
    else            { w = w2; n8 = H2D * HH / 8; q = q2; b0 = bid - 2048; nb = 4096; ssum = sums[1]; dn = (double)H2D * HH; }
    const float inv_s = (float)(dn / ssum);
    for (int i = b0 * 256 + threadIdx.x; i < n8; i += nb * 256) {
        const float4 v0 = ((const float4*)w)[2 * i];
        const float4 v1 = ((const float4*)w)[2 * i + 1];
        union { unsigned short u[8]; uint4 p; } r;
        const float a[8] = {v0.x, v0.y, v0.z, v0.w, v1.x, v1.y, v1.z, v1.w};
        #pragma unroll
        for (int j = 0; j < 8; ++j)
            r.u[j] = f2bf(rintf(fminf(1.f, fmaxf(-1.f, a[j] * inv_s))));
        ((uint4*)q)[i] = r.p;
    }
}

// bf16 embedding gather + masked mean pool; 2 output rows per block; per-row
// counting sort of ids by table window (id>>10) for L2/L3 locality.
__global__ __launch_bounds__(256) void pool_kernel(const int* __restrict__ ids,
                                                   const unsigned short* __restrict__ embh,
                                                   unsigned short* __restrict__ X) {
    const int tid = threadIdx.x;
    const int row = tid >> 7;
    const int t   = tid & 127;
    __shared__ int sid[256];
    __shared__ int sorted_ids[2][128];
    __shared__ int cnt[2][64];
    __shared__ int pos[2][64];
    __shared__ int nz[2];
    sid[tid] = ids[(size_t)blockIdx.x * 256 + tid];
    if (tid < 128) ((int*)cnt)[tid] = 0;
    if (tid < 2) nz[tid] = 0;
    __syncthreads();
    const int myid = sid[tid];
    const int ph = myid >> 10;          // 0..49
    atomicAdd(&cnt[row][ph], 1);
    if (myid != 0) atomicAdd(&nz[row], 1);
    __syncthreads();
    if (tid < 2) {
        int s = 0;
        #pragma unroll
        for (int p = 0; p < 64; ++p) { pos[tid][p] = s; s += cnt[tid][p]; }
    }
    __syncthreads();
    const int where = atomicAdd(&pos[row][ph], 1);
    sorted_ids[row][where] = myid;
    __syncthreads();

    const int col = t * 8;
    float a[8] = {};
    #pragma unroll 8
    for (int s = 0; s < 128; ++s) {
        const int id = sorted_ids[row][s];
        const u16x8 v = *(const u16x8*)(embh + (size_t)id * EE + col);
        #pragma unroll
        for (int j = 0; j < 8; ++j) a[j] += bf2f(v[j]);
    }
    const int c = nz[row];
    const float inv = 1.f / (float)(c ? c : 1);
    u16x8 ov;
    #pragma unroll
    for (int j = 0; j < 8; ++j) ov[j] = f2bf(a[j] * inv);
    const int b = blockIdx.x * 2 + row;
    *(u16x8*)(X + (size_t)b * EE + col) = ov;
}

// GEMM core macro-body shared by the two variants (same m97 structure).
#define GEMM_BODY(K_START, K_END)                                                            \
    __shared__ unsigned short sA[128 * 32];                                                  \
    __shared__ unsigned short sB[128 * 32];                                                  \
    const int tid  = threadIdx.x;                                                            \
    const int wid  = tid >> 6;                                                               \
    const int lane = tid & 63;                                                               \
    const int wm = wid >> 1, wn = wid & 1;                                                   \
    const int quad = lane >> 4;                                                              \
    const int l16  = lane & 15;                                                              \
    const int mBase = blockIdx.y * 128;                                                      \
    const int nBase = blockIdx.x * 128;                                                      \
    f32x4 acc[4][4] = {};                                                                    \
    const int srow = tid >> 2;                                                               \
    const int scol = (tid & 3) * 8;                                                          \
    const size_t aOff0 = (size_t)(mBase + srow) * K + scol;                                  \
    const size_t aOff1 = aOff0 + (size_t)64 * K;                                             \
    const size_t bOff0 = (size_t)(nBase + srow) * K + scol;                                  \
    const size_t bOff1 = bOff0 + (size_t)64 * K;                                             \
    unsigned short* ldsA0 = &sA[wid * 512];                                                  \
    unsigned short* ldsA1 = &sA[2048 + wid * 512];                                           \
    unsigned short* ldsB0 = &sB[wid * 512];                                                  \
    unsigned short* ldsB1 = &sB[2048 + wid * 512];                                           \
    for (int k0 = (K_START); k0 < (K_END); k0 += 32) {                                       \
        __syncthreads();                                                                     \
        __builtin_amdgcn_global_load_lds((const GAS void*)(A + aOff0 + k0), (LAS void*)ldsA0, 16, 0, 0); \
        __builtin_amdgcn_global_load_lds((const GAS void*)(A + aOff1 + k0), (LAS void*)ldsA1, 16, 0, 0); \
        __builtin_amdgcn_global_load_lds((const GAS void*)(B + bOff0 + k0), (LAS void*)ldsB0, 16, 0, 0); \
        __builtin_amdgcn_global_load_lds((const GAS void*)(B + bOff1 + k0), (LAS void*)ldsB1, 16, 0, 0); \
        __syncthreads();                                                                     \
        bf16x8 af[4], bfr[4];                                                                \
        _Pragma("unroll")                                                                    \
        for (int i = 0; i < 4; ++i) {                                                        \
            const int rowA = wm * 64 + i * 16 + l16;                                         \
            af[i]  = *(const bf16x8*)(&sA[rowA * 32 + quad * 8]);                            \
            const int rowB = wn * 64 + i * 16 + l16;                                         \
            bfr[i] = *(const bf16x8*)(&sB[rowB * 32 + quad * 8]);                            \
        }                                                                                    \
        _Pragma("unroll")                                                                    \
        for (int i = 0; i < 4; ++i)                                                          \
            _Pragma("unroll")                                                                \
            for (int j = 0; j < 4; ++j)                                                      \
                acc[i][j] = __builtin_amdgcn_mfma_f32_16x16x32_bf16(af[i], bfr[j], acc[i][j], 0, 0, 0); \
    }

// gemm1: C (bf16) = A[M,K] * B[N,K]^T
__global__ __launch_bounds__(256) void gemm_bt_c16(const unsigned short* __restrict__ A,
                                                   const unsigned short* __restrict__ B,
                                                   unsigned short* __restrict__ C,
                                                   int M, int N, int K) {
    GEMM_BODY(0, K)
    #pragma unroll
    for (int i = 0; i < 4; ++i) {
        const int row0 = mBase + wm * 64 + i * 16 + quad * 4;
        #pragma unroll
        for (int j = 0; j < 4; ++j) {
            const int col = nBase + wn * 64 + j * 16 + l16;
            #pragma unroll
            for (int r = 0; r < 4; ++r)
                C[(size_t)(row0 + r) * N + col] = f2bf(acc[i][j][r]);
        }
    }
}

// gemm2: split-K over gridDim.z=2; fp32 partials into contiguous Cp halves
__global__ __launch_bounds__(256) void gemm_bt_sk2(const unsigned short* __restrict__ A,
                                                   const unsigned short* __restrict__ B,
                                                   float* __restrict__ Cp,
                                                   int M, int N, int K) {
    const int kHalf = K >> 1;
    const int kStart = blockIdx.z * kHalf;
    float* C = Cp + (size_t)blockIdx.z * M * N;
    GEMM_BODY(kStart, kStart + kHalf)
    #pragma unroll
    for (int i = 0; i < 4; ++i) {
        const int row0 = mBase + wm * 64 + i * 16 + quad * 4;
        #pragma unroll
        for (int j = 0; j < 4; ++j) {
            const int col = nBase + wn * 64 + j * 16 + l16;
            #pragma unroll
            for (int r = 0; r < 4; ++r)
                C[(size_t)(row0 + r) * N + col] = acc[i][j][r];
        }
    }
}

// layer-1 LN+GELU: reads bf16 C1
__global__ __launch_bounds__(256) void ln_gelu_c16(const unsigned short* __restrict__ Cm,
                                                   const double* __restrict__ ssum, double nw,
                                                   const float* __restrict__ bias,
                                                   const float* __restrict__ gamma,
                                                   const float* __restrict__ beta,
                                                   unsigned short* __restrict__ H, int N) {
    __shared__ float buf[4096];
    __shared__ float redS[4], redQ[4];
    const int row = blockIdx.x, tid = threadIdx.x;
    const int lane = tid & 63, wid = tid >> 6;
    const float s = (float)(ssum[0] / nw);
    float ps = 0.f, pq = 0.f;
    for (int c = tid; c < N; c += 256) {
        const float y = bf2f(Cm[(size_t)row * N + c]) * s + bias[c];
        buf[c] = y;
        ps += y; pq += y * y;
    }
    for (int o = 32; o; o >>= 1) { ps += __shfl_down(ps, o); pq += __shfl_down(pq, o); }
    if (lane == 0) { redS[wid] = ps; redQ[wid] = pq; }
    __syncthreads();
    const float sum = redS[0] + redS[1] + redS[2] + redS[3];
    const float sq  = redQ[0] + redQ[1] + redQ[2] + redQ[3];
    const float mu  = sum / (float)N;
    float var = sq / (float)N - mu * mu;
    var = fmaxf(var, 0.f);
    const float inv = rsqrtf(var + 1e-5f);
    for (int c = tid; c < N; c += 256) {
        const float y = (buf[c] - mu) * inv * gamma[c] + beta[c];
        const float g = 0.5f * y * (1.f + erff(y * 0.70710678118654752f));
        H[(size_t)row * N + c] = f2bf(g);
    }
}

// layer-2 LN+GELU: sums the two split-K fp32 partials (Ca = Cp, Cb = Cp + M*N)
__global__ __launch_bounds__(256) void ln_gelu_2buf(const float* __restrict__ Ca,
                                                    const float* __restrict__ Cb,
                                                    const double* __restrict__ ssum, double nw,
                                                    const float* __restrict__ bias,
                                                    const float* __restrict__ gamma,
                                                    const float* __restrict__ beta,
                                                    unsigned short* __restrict__ H, int N) {
    __shared__ float buf[2048];
    __shared__ float redS[4], redQ[4];
    const int row = blockIdx.x, tid = threadIdx.x;
    const int lane = tid & 63, wid = tid >> 6;
    const float s = (float)(ssum[0] / nw);
    float ps = 0.f, pq = 0.f;
    for (int c = tid; c < N; c += 256) {
        const size_t idx = (size_t)row * N + c;
        const float y = (Ca[idx] + Cb[idx]) * s + bias[c];
        buf[c] = y;
        ps += y; pq += y * y;
    }
    for (int o = 32; o; o >>= 1) { ps += __shfl_down(ps, o); pq += __shfl_down(pq, o); }
    if (lane == 0) { redS[wid] = ps; redQ[wid] = pq; }
    __syncthreads();
    const float sum = redS[0] + redS[1] + redS[2] + redS[3];
    const float sq  = redQ[0] + redQ[1] + redQ[2] + redQ[3];
    const float mu  = sum / (float)N;
    float var = sq / (float)N - mu * mu;
    var = fmaxf(var, 0.f);
    const float inv = rsqrtf(var + 1e-5f);
    for (int c = tid; c < N; c += 256) {
        const float y = (buf[c] - mu) * inv * gamma[c] + beta[c];
        const float g = 0.5f * y * (1.f + erff(y * 0.70710678118654752f));
        H[(size_t)row * N + c] = f2bf(g);
    }
}

// logits[row, 0..2] = H2[row,:] . ternary(w3)[c,:] + b3  (w3 quantized on the fly)
__global__ __launch_bounds__(256) void final_kernel(const unsigned short* __restrict__ H2,
                                                    const float* __restrict__ w3,
                                                    const double* __restrict__ ssum,
                                                    const float* __restrict__ b3,
                                                    float* __restrict__ out) {
    const int row = blockIdx.x, tid = threadIdx.x;
    const int lane = tid & 63, wid = tid >> 6;
    const float inv_s3 = (float)((double)(3 * H2D) / ssum[0]);
    float a0 = 0.f, a1 = 0.f, a2 = 0.f;
    for (int k = tid; k < H2D; k += 256) {
        const float h = bf2f(H2[(size_t)row * H2D + k]);
        const float q0 = rintf(fminf(1.f, fmaxf(-1.f, w3[k] * inv_s3)));
        const float q1 = rintf(fminf(1.f, fmaxf(-1.f, w3[H2D + k] * inv_s3)));
        const float q2 = rintf(fminf(1.f, fmaxf(-1.f, w3[2 * H2D + k] * inv_s3)));
        a0 += h * q0; a1 += h * q1; a2 += h * q2;
    }
    for (int o = 32; o; o >>= 1) {
        a0 += __shfl_down(a0, o); a1 += __shfl_down(a1, o); a2 += __shfl_down(a2, o);
    }
    __shared__ float r[3][4];
    if (lane == 0) { r[0][wid] = a0; r[1][wid] = a1; r[2][wid] = a2; }
    __syncthreads();
    if (tid < 3) {
        const float s3 = (float)(ssum[0] / (double)(3 * H2D));
        out[(size_t)row * 3 + tid] =
            (r[tid][0] + r[tid][1] + r[tid][2] + r[tid][3]) * s3 + b3[tid];
    }
}

// ---------------- launch ----------------

extern "C" void kernel_launch(void* const* d_in, const int* in_sizes, int n_in,
                              void* d_out, int out_size, void* d_ws, size_t ws_size,
                              hipStream_t stream) {
    const int*   ids = (const int*)d_in[0];
    const float* emb = (const float*)d_in[1];
    const float* w1  = (const float*)d_in[2];
    const float* b1  = (const float*)d_in[3];
    const float* w2  = (const float*)d_in[4];
    const float* b2  = (const float*)d_in[5];
    const float* w3  = (const float*)d_in[6];
    const float* b3  = (const float*)d_in[7];
    const float* g1  = (const float*)d_in[8];
    const float* be1 = (const float*)d_in[9];
    const float* g2  = (const float*)d_in[10];
    const float* be2 = (const float*)d_in[11];
    float* out = (float*)d_out;
    char* ws = (char*)d_ws;

    double*         sums  = (double*)(ws + OFF_S);
    double*         part1 = sums + 8;
    double*         part2 = part1 + 2048;
    unsigned short* X     = (unsigned short*)(ws + OFF_X);
    unsigned short* embh  = (unsigned short*)(ws + OFF_EMBH);
    unsigned short* q1    = (unsigned short*)(ws + OFF_Q1);
    unsigned short* q2    = (unsigned short*)(ws + OFF_Q2);
    unsigned short* C1    = (unsigned short*)(ws + OFF_C1);
    float*          Cp    = (float*)(ws + OFF_C2);
    unsigned short* H1    = (unsigned short*)(ws + OFF_H1);
    unsigned short* H2    = (unsigned short*)(ws + OFF_H2);

    // phase 1: bf16 table + |w| partials (fused, balanced), scales, pool
    prep2_kernel<<<2048, 256, 0, stream>>>(emb, embh, w1, w2, part1, part2);
    reduce_sums<<<3, 256, 0, stream>>>(part1, part2, w3, sums);
    pool_kernel<<<BB / 2, 256, 0, stream>>>(ids, embh, X);

    // phase 2: ternary quant (q1/q2 overlay embh — after pool)
    quant_all<<<6144, 256, 0, stream>>>(w1, w2, sums, q1, q2);

    // phase 3: MLP
    gemm_bt_c16<<<dim3(HH / 128, BB / 128), 256, 0, stream>>>(X, q1, C1, BB, HH, EE);
    ln_gelu_c16<<<BB, 256, 0, stream>>>(C1, sums + 0, (double)HH * (double)EE,
                                        b1, g1, be1, H1, HH);
    gemm_bt_sk2<<<dim3(H2D / 128, BB / 128, 2), 256, 0, stream>>>(H1, q2, Cp, BB, H2D, HH);
    ln_gelu_2buf<<<BB, 256, 0, stream>>>(Cp, Cp + (size_t)BB * H2D, sums + 1,
                                         (double)H2D * (double)HH, b2, g2, be2, H2, H2D);
    final_kernel<<<BB, 256, 0, stream>>>(H2, w3, sums + 2, b3, out);
}